// Round 1
// baseline (32.029 us; speedup 1.0000x reference)
//
#include <hip/hip_runtime.h>
#include <math.h>

// out[b] = bias + sum_{i,j} W[i*D+j] * leaky(cf[b,i]*pf[b,j])
// leaky(z) = 0.55 z + 0.45 |z|;  |cf*pf| = |cf|*|pf|
// => out[b] = bias + sum_j ( 0.55 pf[b,j] G[b,j] + 0.45 |pf[b,j]| H[b,j] )
//    G = cf @ W (over i), H = |cf| @ W (over i)
// Dual-accumulator GEMM (shares every W element for 2 FMAs x 64 batches/tile),
// fused epilogue (linear in G,H so K-split partials atomicAdd directly to out).

constexpr int B = 256, D = 1024;
constexpr int BM = 64, BN = 64, BK = 32;
constexpr int KSPLIT = 8;
constexpr int KCHUNK = D / KSPLIT; // 128

__global__ __launch_bounds__(256) void opl_init(float* __restrict__ out,
                                                const float* __restrict__ bias) {
    out[threadIdx.x] = bias[0];
}

__global__ __launch_bounds__(256, 2) void opl_fused(
    const float* __restrict__ cf, const float* __restrict__ pf,
    const float* __restrict__ W, float* __restrict__ out)
{
    const int bid = blockIdx.x;
    const int mt = bid & 3;          // B/BM  = 4
    const int nt = (bid >> 2) & 15;  // D/BN  = 16
    const int kc = bid >> 6;         // KSPLIT = 8
    const int mbase = mt * BM, nbase = nt * BN, kbase = kc * KCHUNK;

    __shared__ float sW[BK][BN];     // [i][j]
    __shared__ float sC[BK][BM + 4]; // [i][b], +4 pad keeps 16B alignment, spreads banks

    const int tid = threadIdx.x;
    const int tx = tid & 15;   // j-group (4 cols each)
    const int ty = tid >> 4;   // b-group (4 rows each)

    // staging index helpers
    const int wr = tid >> 4;         // W tile row 0..15 (and +16)
    const int wc = (tid & 15) * 4;   // W tile col
    const int cb = tid >> 3;         // cf tile b 0..31 (and +32)
    const int ci = (tid & 7) * 4;    // cf tile i

    float accG[4][4] = {{0.f}};
    float accH[4][4] = {{0.f}};

    for (int k0 = 0; k0 < KCHUNK; k0 += BK) {
        const int kg = kbase + k0;
        const float4 w0 = *reinterpret_cast<const float4*>(&W[(size_t)(kg + wr) * D + nbase + wc]);
        const float4 w1 = *reinterpret_cast<const float4*>(&W[(size_t)(kg + wr + 16) * D + nbase + wc]);
        const float4 c0 = *reinterpret_cast<const float4*>(&cf[(size_t)(mbase + cb) * D + kg + ci]);
        const float4 c1 = *reinterpret_cast<const float4*>(&cf[(size_t)(mbase + cb + 32) * D + kg + ci]);
        *reinterpret_cast<float4*>(&sW[wr][wc]) = w0;
        *reinterpret_cast<float4*>(&sW[wr + 16][wc]) = w1;
        sC[ci + 0][cb] = c0.x; sC[ci + 1][cb] = c0.y;
        sC[ci + 2][cb] = c0.z; sC[ci + 3][cb] = c0.w;
        sC[ci + 0][cb + 32] = c1.x; sC[ci + 1][cb + 32] = c1.y;
        sC[ci + 2][cb + 32] = c1.z; sC[ci + 3][cb + 32] = c1.w;
        __syncthreads();

        #pragma unroll
        for (int k = 0; k < BK; ++k) {
            const float4 wv = *reinterpret_cast<const float4*>(&sW[k][tx * 4]);
            const float4 cv = *reinterpret_cast<const float4*>(&sC[k][ty * 4]);
            const float w[4] = {wv.x, wv.y, wv.z, wv.w};
            const float c[4] = {cv.x, cv.y, cv.z, cv.w};
            #pragma unroll
            for (int r = 0; r < 4; ++r) {
                const float cc = c[r];
                const float aa = fabsf(cc);
                #pragma unroll
                for (int q = 0; q < 4; ++q) {
                    accG[r][q] = fmaf(cc, w[q], accG[r][q]);
                    accH[r][q] = fmaf(aa, w[q], accH[r][q]);
                }
            }
        }
        __syncthreads();
    }

    // fused epilogue: s[r] = sum_q 0.55 p G + 0.45 |p| H for this thread's 4x4 tile
    float s[4];
    #pragma unroll
    for (int r = 0; r < 4; ++r) {
        const int b = mbase + ty * 4 + r;
        const float4 pv = *reinterpret_cast<const float4*>(&pf[(size_t)b * D + nbase + tx * 4]);
        const float p[4] = {pv.x, pv.y, pv.z, pv.w};
        float acc = 0.f;
        #pragma unroll
        for (int q = 0; q < 4; ++q)
            acc += 0.55f * p[q] * accG[r][q] + 0.45f * fabsf(p[q]) * accH[r][q];
        s[r] = acc;
    }
    // reduce across the 16 tx-lanes (they are 16 consecutive lanes of the wave)
    #pragma unroll
    for (int r = 0; r < 4; ++r) {
        s[r] += __shfl_xor(s[r], 1);
        s[r] += __shfl_xor(s[r], 2);
        s[r] += __shfl_xor(s[r], 4);
        s[r] += __shfl_xor(s[r], 8);
    }
    if (tx == 0) {
        #pragma unroll
        for (int r = 0; r < 4; ++r)
            atomicAdd(&out[mbase + ty * 4 + r], s[r]);
    }
}

extern "C" void kernel_launch(void* const* d_in, const int* in_sizes, int n_in,
                              void* d_out, int out_size, void* d_ws, size_t ws_size,
                              hipStream_t stream) {
    const float* cf   = (const float*)d_in[0];
    const float* pf   = (const float*)d_in[1];
    const float* W    = (const float*)d_in[2];
    const float* bias = (const float*)d_in[3];
    float* out = (float*)d_out;

    opl_init<<<1, 256, 0, stream>>>(out, bias);
    opl_fused<<<(B / BM) * (D / BN) * KSPLIT, 256, 0, stream>>>(cf, pf, W, out);
}